// Round 18
// baseline (1299.684 us; speedup 1.0000x reference)
//
#include <hip/hip_runtime.h>
#include <hip/hip_bf16.h>

typedef __hip_bfloat16 bf16;
typedef __attribute__((ext_vector_type(4))) float f32x4;
typedef __attribute__((ext_vector_type(8))) short short8;
typedef __attribute__((ext_vector_type(4))) short short4v;

#define NEGBIG (-3.0e38f)

__device__ __forceinline__ unsigned short f2b(float x) {
  union { float f; unsigned int u; } v; v.f = x;
  unsigned int r = v.u + 0x7fffu + ((v.u >> 16) & 1u);
  return (unsigned short)(r >> 16);
}

__device__ __forceinline__ void gl16(const void* g, void* l) {
  __builtin_amdgcn_global_load_lds(
      (const __attribute__((address_space(1))) unsigned int*)g,
      (__attribute__((address_space(3))) unsigned int*)l, 16, 0, 0);
}

// bijective XCD-grouping swizzle (m204): contiguous tile range per XCD
__device__ __forceinline__ int xcd_swz(int orig, int nwg) {
  const int q = nwg >> 3, r = nwg & 7;
  const int xcd = orig & 7;
  const int base = (xcd < r) ? xcd * (q + 1) : r * (q + 1) + (xcd - r) * q;
  return base + (orig >> 3);
}

// ---------------- weight f32 -> bf16 (row-major) ----------------
__global__ __launch_bounds__(256) void cvt_w_kernel(
    const float* __restrict__ a, const float* __restrict__ b,
    const float* __restrict__ c, const float* __restrict__ d,
    bf16* __restrict__ dst) {
  const int t = blockIdx.x * 256 + threadIdx.x;
  const float* srcs[4] = {a, b, c, d};
#pragma unroll
  for (int w = 0; w < 4; ++w) {
    const f32x4 v = *(const f32x4*)(srcs[w] + (size_t)t * 4);
    short4v o;
    o[0] = (short)f2b(v[0]); o[1] = (short)f2b(v[1]);
    o[2] = (short)f2b(v[2]); o[3] = (short)f2b(v[3]);
    *(short4v*)((short*)dst + (size_t)w * 262144 + (size_t)t * 4) = o;
  }
}

// ---- bias table -> per-(head, frag-element) layout, pads = NEGBIG ----
__global__ __launch_bounds__(256) void prep_rpbL(const float* __restrict__ btab,
                                                 float* __restrict__ rpbL) {
  const int g = blockIdx.x * 256 + threadIdx.x;
  const int lane = g & 63, mn = (g >> 6) & 15, h = g >> 10;
  const int m = mn >> 2, n = mn & 3, l15 = lane & 15, lg = lane >> 4;
  const int cc = n * 16 + l15;
  const int aj = cc / 7, bj = cc % 7;
  f32x4 o;
#pragma unroll
  for (int reg = 0; reg < 4; ++reg) {
    const int i = m * 16 + lg * 4 + reg;
    if (i < 49 && cc < 49) {
      const int t = (i / 7 - aj + 6) * 13 + (i % 7 - bj + 6);
      o[reg] = btab[t * 16 + h];
    } else {
      o[reg] = NEGBIG;
    }
  }
  ((f32x4*)rpbL)[g] = o;
}

// ---- mask -> per-(window, frag-element) layout, pads = 0 ----
__global__ __launch_bounds__(256) void prep_maskL(const float* __restrict__ mask,
                                                  float* __restrict__ maskL) {
  const int g = blockIdx.x * 256 + threadIdx.x;
  const int lane = g & 63, mn = (g >> 6) & 15, wm = g >> 10;
  const int m = mn >> 2, n = mn & 3, l15 = lane & 15, lg = lane >> 4;
  const int cc = n * 16 + l15;
  f32x4 o;
#pragma unroll
  for (int reg = 0; reg < 4; ++reg) {
    const int i = m * 16 + lg * 4 + reg;
    o[reg] = (i < 49 && cc < 49) ? mask[(size_t)wm * 2401 + i * 49 + cc] : 0.f;
  }
  ((f32x4*)maskL)[g] = o;
}

// ---------------- fused KQV GEMM, m97 geometry, f32-A in-LDS convert --------
// grid 6*gy, XCD-swizzled; bn%6: cls = bn>>1 (0=K,1=Q,2=V^T), bnl = bn&1.
// BM=128 (tokens), BN=256 (channels), BK=64, 8 waves. LDS (80KB, 2 blk/CU):
//   Af32 [0,32K): 128x64 f32, linear (gl16 from f32 activations)
//   Abf  [32K,48K): 128x64 bf16, R8 layout/swizzle (convert phase)
//   Bs   [48K,80K): 256x64 bf16, R8 layout/swizzle (gl16 from bf16 weights)
// Pipelined K-step, __syncthreads-only fences:
//   issue B(kt); [kt==0 only: vmcnt(4) to retire prologue A(0) — for kt>=1
//   the previous end-of-step __syncthreads already drained all vmem, so no
//   wait/sched-pin is needed]; convert(kt); __syncthreads; prefetch A(kt+1)
//   into the now-dead Af32; 32-MFMA compute covers its latency; __syncthreads.
__global__ __launch_bounds__(512, 4) void gemm_kqv(
    const float* __restrict__ lf, const float* __restrict__ gfx,
    const short* __restrict__ wbf, const float* __restrict__ bk,
    const float* __restrict__ bq, const float* __restrict__ bv, float qscale,
    bf16* __restrict__ k_ws, bf16* __restrict__ q_ws, bf16* __restrict__ vT_ws,
    int M) {
  __shared__ char lds[81920];
  char* Af32 = lds;           // 32 KB
  char* Abf = lds + 32768;    // 16 KB
  char* Bs = lds + 49152;     // 32 KB
  const int nwg = gridDim.x;
  const int t0 = xcd_swz(blockIdx.x, nwg);
  const int bn = t0 % 6, bm = t0 / 6;
  const int cls = bn >> 1, bnl = bn & 1;
  const int tid = threadIdx.x, lane = tid & 63, wid = tid >> 6;
  const int l15 = lane & 15, lg = lane >> 4;
  const bool swap = (cls == 2);
  // normal: wr (2) x wc (4); swap: cm (4, channels) x ct (2, tokens)
  const int wr = swap ? (wid & 3) : (wid >> 2);
  const int wc = swap ? (wid >> 2) : (wid & 3);
  const float* Af = (cls == 1) ? gfx : lf;
  const char* Bb = (const char*)(wbf + (size_t)cls * 262144);

  f32x4 acc[4][4];
#pragma unroll
  for (int m = 0; m < 4; ++m)
#pragma unroll
    for (int n = 0; n < 4; ++n) acc[m][n] = (f32x4){0.f, 0.f, 0.f, 0.f};

  const char* fam = swap ? Bs : Abf;  // A-operand source (m-axis rows)
  const char* fbm = swap ? Abf : Bs;  // B-operand source (n-axis rows)

  // convert-phase constants (thread t covers f32 slot col tid&15 of rows
  // crow0 + {0,32,64,96} == exactly the slots its own gl16s staged)
  const int crow0 = tid >> 4;
  const int ccol = tid & 15;
  const int c4 = ccol >> 1, hh8 = (ccol & 1) * 8;

#define ISSUE_A(k0)                                                        \
  do {                                                                     \
    _Pragma("unroll") for (int i = 0; i < 4; ++i) {                        \
      const int s = tid + 512 * i;                                         \
      const int row = s >> 4, col = s & 15;                                \
      int gr = bm * 128 + row;                                             \
      if (gr >= M) gr = M - 1; /* clamp: in-bounds source */               \
      gl16((const char*)Af + (size_t)gr * 2048 + (k0) * 4 + col * 16,      \
           Af32 + s * 16);                                                 \
    }                                                                      \
  } while (0)

  // prologue: A(0) in flight
  ISSUE_A(0);

  for (int kt = 0; kt < 8; ++kt) {
    const int k0 = kt * 64;
    // ---- issue B bf16 (4 gl16, R8 swizzled source) ----
#pragma unroll
    for (int i = 0; i < 4; ++i) {
      const int s = tid + 512 * i;
      const int row = s >> 3;
      const int sc = (s & 7) ^ (row & 7);
      gl16(Bb + (size_t)(bnl * 256 + row) * 1024 + k0 * 2 + sc * 16,
           Bs + s * 16);
    }
    // kt==0: retire the prologue A loads (B's 4 stay in flight). For kt>=1
    // the previous end-of-step __syncthreads already drained all vmem, so
    // no wait (and no scheduler pin) is needed.
    if (kt == 0) {
      asm volatile("s_waitcnt vmcnt(4)" ::: "memory");
      __builtin_amdgcn_sched_barrier(0);
    }

    // ---- convert own slots: Af32 -> Abf (R8 layout) ----
#pragma unroll
    for (int j = 0; j < 4; ++j) {
      const int rj = crow0 + 32 * j;
      const f32x4 v = *(const f32x4*)(Af32 + (tid + 512 * j) * 16);
      unsigned int w0, w1;
      asm("v_cvt_pk_bf16_f32 %0, %1, %2" : "=v"(w0) : "v"(v[0]), "v"(v[1]));
      asm("v_cvt_pk_bf16_f32 %0, %1, %2" : "=v"(w1) : "v"(v[2]), "v"(v[3]));
      *(unsigned long long*)(Abf + rj * 128 + (((c4 ^ (rj & 7)) << 4) | hh8)) =
          ((unsigned long long)w1 << 32) | w0;
    }
    __syncthreads();  // drains B gl16s + Abf ds_writes; Af32 now DEAD

    // ---- prefetch A(kt+1) into dead Af32; MFMA cluster covers latency ----
    if (kt < 7) ISSUE_A(k0 + 64);

    // ---- compute: R8-identical read path + MFMA ----
#pragma unroll
    for (int s = 0; s < 2; ++s) {
      short8 af[4], bfr[4];
#pragma unroll
      for (int m = 0; m < 4; ++m) {
        const int r = wr * 64 + m * 16 + l15;
        af[m] = *(const short8*)(fam + r * 128 +
                                 (((s * 4 + lg) ^ (r & 7)) << 4));
      }
#pragma unroll
      for (int n = 0; n < 4; ++n) {
        const int r = wc * 64 + n * 16 + l15;
        bfr[n] = *(const short8*)(fbm + r * 128 +
                                  (((s * 4 + lg) ^ (r & 7)) << 4));
      }
#pragma unroll
      for (int m = 0; m < 4; ++m)
#pragma unroll
        for (int n = 0; n < 4; ++n)
          acc[m][n] = __builtin_amdgcn_mfma_f32_16x16x32_bf16(
              af[m], bfr[n], acc[m][n], 0, 0, 0);
    }
    __syncthreads();  // full fence: drains prefetch (mostly complete) and
                      // orders all LDS reads vs next iteration's writers
  }
#undef ISSUE_A

  if (cls == 2) {  // V^T: m-axis = channels (256), n-axis = tokens (128)
#pragma unroll
    for (int m = 0; m < 4; ++m) {
#pragma unroll
      for (int n = 0; n < 4; ++n) {
        const int tok = bm * 128 + wc * 64 + n * 16 + l15;
        if (tok < M) {
          const int w = tok / 49, nt = tok - w * 49;
#pragma unroll
          for (int reg = 0; reg < 4; ++reg) {
            const int ch = bnl * 256 + wr * 64 + m * 16 + lg * 4 + reg;
            const float v = acc[m][n][reg] + bv[ch];
            const int hh = ch >> 5, dd = ch & 31;
            vT_ws[(((size_t)w * 16 + hh) * 32 + dd) * 64 + nt] =
                __float2bfloat16(v);
          }
        }
      }
    }
  } else {
    const float* bb = (cls == 0) ? bk : bq;
    bf16* dp = (cls == 0) ? k_ws : q_ws;
    const float sc = (cls == 0) ? 1.0f : qscale;
#pragma unroll
    for (int m = 0; m < 4; ++m) {
#pragma unroll
      for (int n = 0; n < 4; ++n) {
        const int c = bnl * 256 + wc * 64 + n * 16 + l15;
        const float bvv = bb[c];
        const int hh = c >> 5, dd = c & 31;
#pragma unroll
        for (int reg = 0; reg < 4; ++reg) {
          const int r = bm * 128 + wr * 64 + m * 16 + lg * 4 + reg;
          if (r < M) {
            const int w = r / 49, nt = r - w * 49;
            dp[(((size_t)w * 16 + hh) * 49 + nt) * 32 + dd] =
                __float2bfloat16((acc[m][n][reg] + bvv) * sc);
          }
        }
      }
    }
  }
}

// ------- m97-geometry staging (proj): A 128x64, B 256x64 bf16, swizzled -----
__device__ __forceinline__ void stage_m97(const char* Ab, const char* Bb,
                                          char* As, char* Bs, int arow0,
                                          int brow0, int k0) {
  const int tid = threadIdx.x;  // 512 threads
#pragma unroll
  for (int i = 0; i < 2; ++i) {
    const int s = tid + 512 * i;  // A: 1024 slots of 16B
    const int row = s >> 3;
    const int sc = (s & 7) ^ (row & 7);
    gl16(Ab + (size_t)(arow0 + row) * 1024 + k0 * 2 + sc * 16, As + s * 16);
  }
#pragma unroll
  for (int i = 0; i < 4; ++i) {
    const int s = tid + 512 * i;  // B: 2048 slots of 16B
    const int row = s >> 3;
    const int sc = (s & 7) ^ (row & 7);
    gl16(Bb + (size_t)(brow0 + row) * 1024 + k0 * 2 + sc * 16, Bs + s * 16);
  }
}

// ---------------- proj GEMM, m97 geometry: f32 out [r][512] -----------------
__global__ __launch_bounds__(512, 4) void gemm_p(const short* __restrict__ Abf,
                                                 const short* __restrict__ Bbf,
                                                 const float* __restrict__ bias,
                                                 float* __restrict__ dst,
                                                 int M) {
  __shared__ char lds[49152];
  char* As = lds;
  char* Bs = lds + 16384;
  const int nwg = gridDim.x;
  const int t0 = xcd_swz(blockIdx.x, nwg);
  const int bnl = t0 & 1, bm = t0 >> 1;
  const int tid = threadIdx.x, lane = tid & 63, wid = tid >> 6;
  const int wr = wid >> 2, wc = wid & 3, l15 = lane & 15, lg = lane >> 4;

  f32x4 acc[4][4];
#pragma unroll
  for (int m = 0; m < 4; ++m)
#pragma unroll
    for (int n = 0; n < 4; ++n) acc[m][n] = (f32x4){0.f, 0.f, 0.f, 0.f};

  for (int kt = 0; kt < 8; ++kt) {
    stage_m97((const char*)Abf, (const char*)Bbf, As, Bs, bm * 128, bnl * 256,
              kt * 64);
    __syncthreads();
#pragma unroll
    for (int s = 0; s < 2; ++s) {
      short8 af[4], bfr[4];
#pragma unroll
      for (int m = 0; m < 4; ++m) {
        const int r = wr * 64 + m * 16 + l15;
        af[m] = *(const short8*)(As + r * 128 +
                                 (((s * 4 + lg) ^ (r & 7)) << 4));
      }
#pragma unroll
      for (int n = 0; n < 4; ++n) {
        const int r = wc * 64 + n * 16 + l15;
        bfr[n] = *(const short8*)(Bs + r * 128 +
                                  (((s * 4 + lg) ^ (r & 7)) << 4));
      }
#pragma unroll
      for (int m = 0; m < 4; ++m)
#pragma unroll
        for (int n = 0; n < 4; ++n)
          acc[m][n] = __builtin_amdgcn_mfma_f32_16x16x32_bf16(
              af[m], bfr[n], acc[m][n], 0, 0, 0);
    }
    __syncthreads();
  }

#pragma unroll
  for (int m = 0; m < 4; ++m) {
#pragma unroll
    for (int n = 0; n < 4; ++n) {
      const int c = bnl * 256 + wc * 64 + n * 16 + l15;
      const float bvv = bias[c];
#pragma unroll
      for (int reg = 0; reg < 4; ++reg) {
        const int r = bm * 128 + wr * 64 + m * 16 + lg * 4 + reg;
        if (r < M) dst[(size_t)r * 512 + c] = acc[m][n][reg] + bvv;
      }
    }
  }
}

// ---------------- windowed attention: 1 head per wave, no barriers ---------
__global__ __launch_bounds__(256) void attn_win2(
    const bf16* __restrict__ q_ws, const bf16* __restrict__ k_ws,
    const bf16* __restrict__ vT_ws, const float* __restrict__ rpbL,
    const float* __restrict__ maskL, bf16* __restrict__ x_ws, int wstart) {
  __shared__ short sP[4][4096];
  const int tid = threadIdx.x, lane = tid & 63, wid = tid >> 6;
  const int l15 = lane & 15, lg = lane >> 4;
  const int wl = blockIdx.x;
  const int h = blockIdx.y * 4 + wid;
  const int wg = wstart + wl;
  char* Pl = (char*)sP[wid];
  const size_t base = ((size_t)wl * 16 + h) * 1568;
  const short8 z8 = (short8){0, 0, 0, 0, 0, 0, 0, 0};

  short8 qf[4], kf[4];
#pragma unroll
  for (int m = 0; m < 4; ++m) {
    const int r = m * 16 + l15;
    qf[m] = (r < 49) ? *(const short8*)(q_ws + base + r * 32 + lg * 8) : z8;
    kf[m] = (r < 49) ? *(const short8*)(k_ws + base + r * 32 + lg * 8) : z8;
  }
  f32x4 lc[4][4];
  __builtin_amdgcn_s_setprio(1);
#pragma unroll
  for (int m = 0; m < 4; ++m)
#pragma unroll
    for (int n = 0; n < 4; ++n)
      lc[m][n] = __builtin_amdgcn_mfma_f32_16x16x32_bf16(
          qf[m], kf[n], (f32x4){0.f, 0.f, 0.f, 0.f}, 0, 0, 0);
  __builtin_amdgcn_s_setprio(0);

  const f32x4* rbp = (const f32x4*)rpbL + (size_t)h * 1024 + lane;
  const f32x4* mkp = (const f32x4*)maskL + (size_t)(wg & 1023) * 1024 + lane;
#pragma unroll
  for (int m = 0; m < 4; ++m)
#pragma unroll
    for (int n = 0; n < 4; ++n) {
      const int mn = m * 4 + n;
      lc[m][n] += rbp[mn * 64] + mkp[mn * 64];
    }

#pragma unroll
  for (int m = 0; m < 4; ++m) {
#pragma unroll
    for (int reg = 0; reg < 4; ++reg) {
      float vmax = fmaxf(fmaxf(lc[m][0][reg], lc[m][1][reg]),
                         fmaxf(lc[m][2][reg], lc[m][3][reg]));
#pragma unroll
      for (int off = 1; off < 16; off <<= 1)
        vmax = fmaxf(vmax, __shfl_xor(vmax, off, 64));
      float e[4], ssum = 0.f;
#pragma unroll
      for (int n = 0; n < 4; ++n) {
        e[n] = __expf(lc[m][n][reg] - vmax);
        ssum += e[n];
      }
#pragma unroll
      for (int off = 1; off < 16; off <<= 1) ssum += __shfl_xor(ssum, off, 64);
      const float inv = __builtin_amdgcn_rcpf(ssum);
      const int i = m * 16 + lg * 4 + reg;
#pragma unroll
      for (int n = 0; n < 4; ++n) {
        const int cc = n * 16 + l15;
        *(unsigned short*)(Pl + i * 128 + ((2 * cc) ^ ((i & 7) << 4))) =
            f2b(e[n] * inv);
      }
    }
  }

  f32x4 xacc[4][2];
#pragma unroll
  for (int m = 0; m < 4; ++m)
#pragma unroll
    for (int n = 0; n < 2; ++n) xacc[m][n] = (f32x4){0.f, 0.f, 0.f, 0.f};
  const size_t vbase = ((size_t)wl * 16 + h) * 2048;
#pragma unroll
  for (int s = 0; s < 2; ++s) {
    short8 pf[4], vf[2];
#pragma unroll
    for (int m = 0; m < 4; ++m) {
      const int i = m * 16 + l15;
      pf[m] = *(const short8*)(Pl + i * 128 +
                               ((s * 64 + lg * 16) ^ ((i & 7) << 4)));
    }
#pragma unroll
    for (int n = 0; n < 2; ++n) {
      const int dd = n * 16 + l15;
      short8 vv = *(const short8*)(vT_ws + vbase + dd * 64 + s * 32 + lg * 8);
      if (s == 1) {
        if (lg == 3) vv = z8;
        else if (lg == 2) {
          vv[1] = 0; vv[2] = 0; vv[3] = 0; vv[4] = 0;
          vv[5] = 0; vv[6] = 0; vv[7] = 0;
        }
      }
      vf[n] = vv;
    }
    __builtin_amdgcn_s_setprio(1);
#pragma unroll
    for (int m = 0; m < 4; ++m)
#pragma unroll
      for (int n = 0; n < 2; ++n)
        xacc[m][n] = __builtin_amdgcn_mfma_f32_16x16x32_bf16(
            pf[m], vf[n], xacc[m][n], 0, 0, 0);
    __builtin_amdgcn_s_setprio(0);
  }

#pragma unroll
  for (int m = 0; m < 4; ++m)
#pragma unroll
    for (int n = 0; n < 2; ++n)
#pragma unroll
      for (int reg = 0; reg < 4; ++reg) {
        const int i = m * 16 + lg * 4 + reg;
        const int dd = n * 16 + l15;
        *(unsigned short*)(Pl + i * 80 + ((2 * dd) ^ ((i & 3) << 4))) =
            f2b(xacc[m][n][reg]);
      }
#pragma unroll
  for (int g = 0; g < 4; ++g) {
    const int row = g * 16 + (lane >> 2);
    if (row < 49) {
      const short8 xv = *(const short8*)(
          Pl + row * 80 + (((lane & 3) * 16) ^ ((row & 3) << 4)));
      *(short8*)(x_ws + ((size_t)wl * 49 + row) * 512 + h * 32 +
                 (lane & 3) * 8) = xv;
    }
  }
}

extern "C" void kernel_launch(void* const* d_in, const int* in_sizes, int n_in,
                              void* d_out, int out_size, void* d_ws,
                              size_t ws_size, hipStream_t stream) {
  const float* lf   = (const float*)d_in[0];
  const float* gfx  = (const float*)d_in[1];
  const float* mask = (const float*)d_in[2];
  const float* btab = (const float*)d_in[3];
  const float* Wk = (const float*)d_in[4];  const float* bk = (const float*)d_in[5];
  const float* Wq = (const float*)d_in[6];  const float* bq = (const float*)d_in[7];
  const float* Wv = (const float*)d_in[8];  const float* bv = (const float*)d_in[9];
  const float* Wp = (const float*)d_in[10]; const float* bp = (const float*)d_in[11];
  float* out = (float*)d_out;

  char* ws = (char*)d_ws;
  short* wbf = (short*)ws;  // 4 x 512x512 bf16 = 2 MB
  size_t off = (size_t)4 * 262144 * 2;
  float* rpbL = (float*)(ws + off); off += (size_t)16 * 4096 * 4;     // 256 KB
  float* maskL = (float*)(ws + off); off += (size_t)1024 * 4096 * 4;  // 16 MB

  const size_t perw = 50176 + 2 * 50176 + 65536;  // x,q,k + vT = 216064 B
  size_t avail = (ws_size > off + 65536) ? ws_size - off - 65536 : 0;
  int CH = (int)(avail / perw);
  if (CH > 4096) CH = 4096;
  if (CH < 1) CH = 1;

  bf16* x_ws = (bf16*)(ws + off); off += (size_t)CH * 50176;
  bf16* q_ws = (bf16*)(ws + off); off += (size_t)CH * 50176;
  bf16* k_ws = (bf16*)(ws + off); off += (size_t)CH * 50176;
  bf16* vT_ws = (bf16*)(ws + off); off += (size_t)CH * 65536;

  cvt_w_kernel<<<256, 256, 0, stream>>>(Wk, Wq, Wv, Wp, (bf16*)wbf);
  prep_rpbL<<<64, 256, 0, stream>>>(btab, rpbL);
  prep_maskL<<<4096, 256, 0, stream>>>(mask, maskL);

  const float qscale = 0.17677669529663687f;  // 1/sqrt(32)
  for (int wstart = 0; wstart < 4096; wstart += CH) {
    const int nwin = (4096 - wstart < CH) ? (4096 - wstart) : CH;
    const int M = nwin * 49;
    const int gy = (M + 127) / 128;
    gemm_kqv<<<6 * gy, 512, 0, stream>>>(lf + (size_t)wstart * 25088,
                                         gfx + (size_t)wstart * 25088, wbf,
                                         bk, bq, bv, qscale, k_ws, q_ws,
                                         vT_ws, M);
    attn_win2<<<dim3(nwin, 4), 256, 0, stream>>>(q_ws, k_ws, vT_ws, rpbL,
                                                 maskL, x_ws, wstart);
    gemm_p<<<2 * gy, 512, 0, stream>>>((const short*)x_ws, wbf + 3 * 262144,
                                       bp, out + (size_t)wstart * 25088, M);
  }
}

// Round 19
// 1149.511 us; speedup vs baseline: 1.1306x; 1.1306x over previous
//
#include <hip/hip_runtime.h>
#include <hip/hip_bf16.h>

typedef __hip_bfloat16 bf16;
typedef __attribute__((ext_vector_type(4))) float f32x4;
typedef __attribute__((ext_vector_type(8))) short short8;
typedef __attribute__((ext_vector_type(4))) short short4v;

#define NEGBIG (-3.0e38f)

__device__ __forceinline__ unsigned short f2b(float x) {
  union { float f; unsigned int u; } v; v.f = x;
  unsigned int r = v.u + 0x7fffu + ((v.u >> 16) & 1u);
  return (unsigned short)(r >> 16);
}

__device__ __forceinline__ void gl16(const void* g, void* l) {
  __builtin_amdgcn_global_load_lds(
      (const __attribute__((address_space(1))) unsigned int*)g,
      (__attribute__((address_space(3))) unsigned int*)l, 16, 0, 0);
}

// bijective XCD-grouping swizzle (m204): contiguous tile range per XCD
__device__ __forceinline__ int xcd_swz(int orig, int nwg) {
  const int q = nwg >> 3, r = nwg & 7;
  const int xcd = orig & 7;
  const int base = (xcd < r) ? xcd * (q + 1) : r * (q + 1) + (xcd - r) * q;
  return base + (orig >> 3);
}

// ---------------- weight f32 -> bf16 (row-major) ----------------
__global__ __launch_bounds__(256) void cvt_w_kernel(
    const float* __restrict__ a, const float* __restrict__ b,
    const float* __restrict__ c, const float* __restrict__ d,
    bf16* __restrict__ dst) {
  const int t = blockIdx.x * 256 + threadIdx.x;
  const float* srcs[4] = {a, b, c, d};
#pragma unroll
  for (int w = 0; w < 4; ++w) {
    const f32x4 v = *(const f32x4*)(srcs[w] + (size_t)t * 4);
    short4v o;
    o[0] = (short)f2b(v[0]); o[1] = (short)f2b(v[1]);
    o[2] = (short)f2b(v[2]); o[3] = (short)f2b(v[3]);
    *(short4v*)((short*)dst + (size_t)w * 262144 + (size_t)t * 4) = o;
  }
}

// ---- bias table -> per-(head, frag-element) layout, pads = NEGBIG ----
__global__ __launch_bounds__(256) void prep_rpbL(const float* __restrict__ btab,
                                                 float* __restrict__ rpbL) {
  const int g = blockIdx.x * 256 + threadIdx.x;
  const int lane = g & 63, mn = (g >> 6) & 15, h = g >> 10;
  const int m = mn >> 2, n = mn & 3, l15 = lane & 15, lg = lane >> 4;
  const int cc = n * 16 + l15;
  const int aj = cc / 7, bj = cc % 7;
  f32x4 o;
#pragma unroll
  for (int reg = 0; reg < 4; ++reg) {
    const int i = m * 16 + lg * 4 + reg;
    if (i < 49 && cc < 49) {
      const int t = (i / 7 - aj + 6) * 13 + (i % 7 - bj + 6);
      o[reg] = btab[t * 16 + h];
    } else {
      o[reg] = NEGBIG;
    }
  }
  ((f32x4*)rpbL)[g] = o;
}

// ---- mask -> per-(window, frag-element) layout, pads = 0 ----
__global__ __launch_bounds__(256) void prep_maskL(const float* __restrict__ mask,
                                                  float* __restrict__ maskL) {
  const int g = blockIdx.x * 256 + threadIdx.x;
  const int lane = g & 63, mn = (g >> 6) & 15, wm = g >> 10;
  const int m = mn >> 2, n = mn & 3, l15 = lane & 15, lg = lane >> 4;
  const int cc = n * 16 + l15;
  f32x4 o;
#pragma unroll
  for (int reg = 0; reg < 4; ++reg) {
    const int i = m * 16 + lg * 4 + reg;
    o[reg] = (i < 49 && cc < 49) ? mask[(size_t)wm * 2401 + i * 49 + cc] : 0.f;
  }
  ((f32x4*)maskL)[g] = o;
}

// ---------------- fused KQV GEMM, m97 geometry, f32-A in-LDS convert --------
// grid 6*gy, XCD-swizzled; bn%6: cls = bn>>1 (0=K,1=Q,2=V^T), bnl = bn&1.
// BM=128 (tokens), BN=256 (channels), BK=64, 8 waves. LDS (80KB, 2 blk/CU):
//   Af32 [0,32K): 128x64 f32, linear (gl16 from f32 activations)
//   Abf  [32K,48K): 128x64 bf16, R8 layout/swizzle (convert phase)
//   Bs   [48K,80K): 256x64 bf16, R8 layout/swizzle (gl16 from bf16 weights)
// Pipelined K-step, __syncthreads-only fences:
//   issue B(kt); vmcnt(4) [retires A(kt); ALSO acts as an issue-rate governor
//   keeping co-resident blocks phase-locked for L2 dedup — removing it (R18)
//   ballooned HBM traffic 1.7x]; convert(kt); __syncthreads; prefetch A(kt+1)
//   into the now-dead Af32; 32-MFMA compute covers its latency; __syncthreads.
__global__ __launch_bounds__(512, 4) void gemm_kqv(
    const float* __restrict__ lf, const float* __restrict__ gfx,
    const short* __restrict__ wbf, const float* __restrict__ bk,
    const float* __restrict__ bq, const float* __restrict__ bv, float qscale,
    bf16* __restrict__ k_ws, bf16* __restrict__ q_ws, bf16* __restrict__ vT_ws,
    int M) {
  __shared__ char lds[81920];
  char* Af32 = lds;           // 32 KB
  char* Abf = lds + 32768;    // 16 KB
  char* Bs = lds + 49152;     // 32 KB
  const int nwg = gridDim.x;
  const int t0 = xcd_swz(blockIdx.x, nwg);
  const int bn = t0 % 6, bm = t0 / 6;
  const int cls = bn >> 1, bnl = bn & 1;
  const int tid = threadIdx.x, lane = tid & 63, wid = tid >> 6;
  const int l15 = lane & 15, lg = lane >> 4;
  const bool swap = (cls == 2);
  // normal: wr (2) x wc (4); swap: cm (4, channels) x ct (2, tokens)
  const int wr = swap ? (wid & 3) : (wid >> 2);
  const int wc = swap ? (wid >> 2) : (wid & 3);
  const float* Af = (cls == 1) ? gfx : lf;
  const char* Bb = (const char*)(wbf + (size_t)cls * 262144);

  f32x4 acc[4][4];
#pragma unroll
  for (int m = 0; m < 4; ++m)
#pragma unroll
    for (int n = 0; n < 4; ++n) acc[m][n] = (f32x4){0.f, 0.f, 0.f, 0.f};

  const char* fam = swap ? Bs : Abf;  // A-operand source (m-axis rows)
  const char* fbm = swap ? Abf : Bs;  // B-operand source (n-axis rows)

  // convert-phase constants (thread t covers f32 slot col tid&15 of rows
  // crow0 + {0,32,64,96} == exactly the slots its own gl16s staged)
  const int crow0 = tid >> 4;
  const int ccol = tid & 15;
  const int c4 = ccol >> 1, hh8 = (ccol & 1) * 8;

#define ISSUE_A(k0)                                                        \
  do {                                                                     \
    _Pragma("unroll") for (int i = 0; i < 4; ++i) {                        \
      const int s = tid + 512 * i;                                         \
      const int row = s >> 4, col = s & 15;                                \
      int gr = bm * 128 + row;                                             \
      if (gr >= M) gr = M - 1; /* clamp: in-bounds source */               \
      gl16((const char*)Af + (size_t)gr * 2048 + (k0) * 4 + col * 16,      \
           Af32 + s * 16);                                                 \
    }                                                                      \
  } while (0)

  // prologue: A(0) in flight
  ISSUE_A(0);

  for (int kt = 0; kt < 8; ++kt) {
    const int k0 = kt * 64;
    // ---- issue B bf16 (4 gl16, R8 swizzled source) ----
#pragma unroll
    for (int i = 0; i < 4; ++i) {
      const int s = tid + 512 * i;
      const int row = s >> 3;
      const int sc = (s & 7) ^ (row & 7);
      gl16(Bb + (size_t)(bnl * 256 + row) * 1024 + k0 * 2 + sc * 16,
           Bs + s * 16);
    }
    // retire this thread's A loads (no-op in steady state for correctness,
    // but REQUIRED for performance: acts as an issue-rate governor that
    // keeps co-resident blocks phase-locked -> L2 dedup (R18 post-mortem)
    asm volatile("s_waitcnt vmcnt(4)" ::: "memory");
    __builtin_amdgcn_sched_barrier(0);

    // ---- convert own slots: Af32 -> Abf (R8 layout) ----
#pragma unroll
    for (int j = 0; j < 4; ++j) {
      const int rj = crow0 + 32 * j;
      const f32x4 v = *(const f32x4*)(Af32 + (tid + 512 * j) * 16);
      unsigned int w0, w1;
      asm("v_cvt_pk_bf16_f32 %0, %1, %2" : "=v"(w0) : "v"(v[0]), "v"(v[1]));
      asm("v_cvt_pk_bf16_f32 %0, %1, %2" : "=v"(w1) : "v"(v[2]), "v"(v[3]));
      *(unsigned long long*)(Abf + rj * 128 + (((c4 ^ (rj & 7)) << 4) | hh8)) =
          ((unsigned long long)w1 << 32) | w0;
    }
    __syncthreads();  // drains B gl16s + Abf ds_writes; Af32 now DEAD

    // ---- prefetch A(kt+1) into dead Af32; MFMA cluster covers latency ----
    if (kt < 7) ISSUE_A(k0 + 64);

    // ---- compute: R8-identical read path + MFMA ----
#pragma unroll
    for (int s = 0; s < 2; ++s) {
      short8 af[4], bfr[4];
#pragma unroll
      for (int m = 0; m < 4; ++m) {
        const int r = wr * 64 + m * 16 + l15;
        af[m] = *(const short8*)(fam + r * 128 +
                                 (((s * 4 + lg) ^ (r & 7)) << 4));
      }
#pragma unroll
      for (int n = 0; n < 4; ++n) {
        const int r = wc * 64 + n * 16 + l15;
        bfr[n] = *(const short8*)(fbm + r * 128 +
                                  (((s * 4 + lg) ^ (r & 7)) << 4));
      }
#pragma unroll
      for (int m = 0; m < 4; ++m)
#pragma unroll
        for (int n = 0; n < 4; ++n)
          acc[m][n] = __builtin_amdgcn_mfma_f32_16x16x32_bf16(
              af[m], bfr[n], acc[m][n], 0, 0, 0);
    }
    __syncthreads();  // full fence: drains prefetch (mostly complete) and
                      // orders all LDS reads vs next iteration's writers
  }
#undef ISSUE_A

  if (cls == 2) {  // V^T: m-axis = channels (256), n-axis = tokens (128)
#pragma unroll
    for (int m = 0; m < 4; ++m) {
#pragma unroll
      for (int n = 0; n < 4; ++n) {
        const int tok = bm * 128 + wc * 64 + n * 16 + l15;
        if (tok < M) {
          const int w = tok / 49, nt = tok - w * 49;
#pragma unroll
          for (int reg = 0; reg < 4; ++reg) {
            const int ch = bnl * 256 + wr * 64 + m * 16 + lg * 4 + reg;
            const float v = acc[m][n][reg] + bv[ch];
            const int hh = ch >> 5, dd = ch & 31;
            vT_ws[(((size_t)w * 16 + hh) * 32 + dd) * 64 + nt] =
                __float2bfloat16(v);
          }
        }
      }
    }
  } else {
    const float* bb = (cls == 0) ? bk : bq;
    bf16* dp = (cls == 0) ? k_ws : q_ws;
    const float sc = (cls == 0) ? 1.0f : qscale;
#pragma unroll
    for (int m = 0; m < 4; ++m) {
#pragma unroll
      for (int n = 0; n < 4; ++n) {
        const int c = bnl * 256 + wc * 64 + n * 16 + l15;
        const float bvv = bb[c];
        const int hh = c >> 5, dd = c & 31;
#pragma unroll
        for (int reg = 0; reg < 4; ++reg) {
          const int r = bm * 128 + wr * 64 + m * 16 + lg * 4 + reg;
          if (r < M) {
            const int w = r / 49, nt = r - w * 49;
            dp[(((size_t)w * 16 + hh) * 49 + nt) * 32 + dd] =
                __float2bfloat16((acc[m][n][reg] + bvv) * sc);
          }
        }
      }
    }
  }
}

// ------- m97-geometry staging (proj): A 128x64, B 256x64 bf16, swizzled -----
__device__ __forceinline__ void stage_m97(const char* Ab, const char* Bb,
                                          char* As, char* Bs, int arow0,
                                          int brow0, int k0) {
  const int tid = threadIdx.x;  // 512 threads
#pragma unroll
  for (int i = 0; i < 2; ++i) {
    const int s = tid + 512 * i;  // A: 1024 slots of 16B
    const int row = s >> 3;
    const int sc = (s & 7) ^ (row & 7);
    gl16(Ab + (size_t)(arow0 + row) * 1024 + k0 * 2 + sc * 16, As + s * 16);
  }
#pragma unroll
  for (int i = 0; i < 4; ++i) {
    const int s = tid + 512 * i;  // B: 2048 slots of 16B
    const int row = s >> 3;
    const int sc = (s & 7) ^ (row & 7);
    gl16(Bb + (size_t)(brow0 + row) * 1024 + k0 * 2 + sc * 16, Bs + s * 16);
  }
}

// ---------------- proj GEMM, m97 geometry: f32 out [r][512] -----------------
__global__ __launch_bounds__(512, 4) void gemm_p(const short* __restrict__ Abf,
                                                 const short* __restrict__ Bbf,
                                                 const float* __restrict__ bias,
                                                 float* __restrict__ dst,
                                                 int M) {
  __shared__ char lds[49152];
  char* As = lds;
  char* Bs = lds + 16384;
  const int nwg = gridDim.x;
  const int t0 = xcd_swz(blockIdx.x, nwg);
  const int bnl = t0 & 1, bm = t0 >> 1;
  const int tid = threadIdx.x, lane = tid & 63, wid = tid >> 6;
  const int wr = wid >> 2, wc = wid & 3, l15 = lane & 15, lg = lane >> 4;

  f32x4 acc[4][4];
#pragma unroll
  for (int m = 0; m < 4; ++m)
#pragma unroll
    for (int n = 0; n < 4; ++n) acc[m][n] = (f32x4){0.f, 0.f, 0.f, 0.f};

  for (int kt = 0; kt < 8; ++kt) {
    stage_m97((const char*)Abf, (const char*)Bbf, As, Bs, bm * 128, bnl * 256,
              kt * 64);
    __syncthreads();
#pragma unroll
    for (int s = 0; s < 2; ++s) {
      short8 af[4], bfr[4];
#pragma unroll
      for (int m = 0; m < 4; ++m) {
        const int r = wr * 64 + m * 16 + l15;
        af[m] = *(const short8*)(As + r * 128 +
                                 (((s * 4 + lg) ^ (r & 7)) << 4));
      }
#pragma unroll
      for (int n = 0; n < 4; ++n) {
        const int r = wc * 64 + n * 16 + l15;
        bfr[n] = *(const short8*)(Bs + r * 128 +
                                  (((s * 4 + lg) ^ (r & 7)) << 4));
      }
#pragma unroll
      for (int m = 0; m < 4; ++m)
#pragma unroll
        for (int n = 0; n < 4; ++n)
          acc[m][n] = __builtin_amdgcn_mfma_f32_16x16x32_bf16(
              af[m], bfr[n], acc[m][n], 0, 0, 0);
    }
    __syncthreads();
  }

#pragma unroll
  for (int m = 0; m < 4; ++m) {
#pragma unroll
    for (int n = 0; n < 4; ++n) {
      const int c = bnl * 256 + wc * 64 + n * 16 + l15;
      const float bvv = bias[c];
#pragma unroll
      for (int reg = 0; reg < 4; ++reg) {
        const int r = bm * 128 + wr * 64 + m * 16 + lg * 4 + reg;
        if (r < M) dst[(size_t)r * 512 + c] = acc[m][n][reg] + bvv;
      }
    }
  }
}

// ---------------- windowed attention: 1 head per wave, no barriers ---------
__global__ __launch_bounds__(256) void attn_win2(
    const bf16* __restrict__ q_ws, const bf16* __restrict__ k_ws,
    const bf16* __restrict__ vT_ws, const float* __restrict__ rpbL,
    const float* __restrict__ maskL, bf16* __restrict__ x_ws, int wstart) {
  __shared__ short sP[4][4096];
  const int tid = threadIdx.x, lane = tid & 63, wid = tid >> 6;
  const int l15 = lane & 15, lg = lane >> 4;
  const int wl = blockIdx.x;
  const int h = blockIdx.y * 4 + wid;
  const int wg = wstart + wl;
  char* Pl = (char*)sP[wid];
  const size_t base = ((size_t)wl * 16 + h) * 1568;
  const short8 z8 = (short8){0, 0, 0, 0, 0, 0, 0, 0};

  short8 qf[4], kf[4];
#pragma unroll
  for (int m = 0; m < 4; ++m) {
    const int r = m * 16 + l15;
    qf[m] = (r < 49) ? *(const short8*)(q_ws + base + r * 32 + lg * 8) : z8;
    kf[m] = (r < 49) ? *(const short8*)(k_ws + base + r * 32 + lg * 8) : z8;
  }
  f32x4 lc[4][4];
  __builtin_amdgcn_s_setprio(1);
#pragma unroll
  for (int m = 0; m < 4; ++m)
#pragma unroll
    for (int n = 0; n < 4; ++n)
      lc[m][n] = __builtin_amdgcn_mfma_f32_16x16x32_bf16(
          qf[m], kf[n], (f32x4){0.f, 0.f, 0.f, 0.f}, 0, 0, 0);
  __builtin_amdgcn_s_setprio(0);

  const f32x4* rbp = (const f32x4*)rpbL + (size_t)h * 1024 + lane;
  const f32x4* mkp = (const f32x4*)maskL + (size_t)(wg & 1023) * 1024 + lane;
#pragma unroll
  for (int m = 0; m < 4; ++m)
#pragma unroll
    for (int n = 0; n < 4; ++n) {
      const int mn = m * 4 + n;
      lc[m][n] += rbp[mn * 64] + mkp[mn * 64];
    }

#pragma unroll
  for (int m = 0; m < 4; ++m) {
#pragma unroll
    for (int reg = 0; reg < 4; ++reg) {
      float vmax = fmaxf(fmaxf(lc[m][0][reg], lc[m][1][reg]),
                         fmaxf(lc[m][2][reg], lc[m][3][reg]));
#pragma unroll
      for (int off = 1; off < 16; off <<= 1)
        vmax = fmaxf(vmax, __shfl_xor(vmax, off, 64));
      float e[4], ssum = 0.f;
#pragma unroll
      for (int n = 0; n < 4; ++n) {
        e[n] = __expf(lc[m][n][reg] - vmax);
        ssum += e[n];
      }
#pragma unroll
      for (int off = 1; off < 16; off <<= 1) ssum += __shfl_xor(ssum, off, 64);
      const float inv = __builtin_amdgcn_rcpf(ssum);
      const int i = m * 16 + lg * 4 + reg;
#pragma unroll
      for (int n = 0; n < 4; ++n) {
        const int cc = n * 16 + l15;
        *(unsigned short*)(Pl + i * 128 + ((2 * cc) ^ ((i & 7) << 4))) =
            f2b(e[n] * inv);
      }
    }
  }

  f32x4 xacc[4][2];
#pragma unroll
  for (int m = 0; m < 4; ++m)
#pragma unroll
    for (int n = 0; n < 2; ++n) xacc[m][n] = (f32x4){0.f, 0.f, 0.f, 0.f};
  const size_t vbase = ((size_t)wl * 16 + h) * 2048;
#pragma unroll
  for (int s = 0; s < 2; ++s) {
    short8 pf[4], vf[2];
#pragma unroll
    for (int m = 0; m < 4; ++m) {
      const int i = m * 16 + l15;
      pf[m] = *(const short8*)(Pl + i * 128 +
                               ((s * 64 + lg * 16) ^ ((i & 7) << 4)));
    }
#pragma unroll
    for (int n = 0; n < 2; ++n) {
      const int dd = n * 16 + l15;
      short8 vv = *(const short8*)(vT_ws + vbase + dd * 64 + s * 32 + lg * 8);
      if (s == 1) {
        if (lg == 3) vv = z8;
        else if (lg == 2) {
          vv[1] = 0; vv[2] = 0; vv[3] = 0; vv[4] = 0;
          vv[5] = 0; vv[6] = 0; vv[7] = 0;
        }
      }
      vf[n] = vv;
    }
    __builtin_amdgcn_s_setprio(1);
#pragma unroll
    for (int m = 0; m < 4; ++m)
#pragma unroll
      for (int n = 0; n < 2; ++n)
        xacc[m][n] = __builtin_amdgcn_mfma_f32_16x16x32_bf16(
            pf[m], vf[n], xacc[m][n], 0, 0, 0);
    __builtin_amdgcn_s_setprio(0);
  }

#pragma unroll
  for (int m = 0; m < 4; ++m)
#pragma unroll
    for (int n = 0; n < 2; ++n)
#pragma unroll
      for (int reg = 0; reg < 4; ++reg) {
        const int i = m * 16 + lg * 4 + reg;
        const int dd = n * 16 + l15;
        *(unsigned short*)(Pl + i * 80 + ((2 * dd) ^ ((i & 3) << 4))) =
            f2b(xacc[m][n][reg]);
      }
#pragma unroll
  for (int g = 0; g < 4; ++g) {
    const int row = g * 16 + (lane >> 2);
    if (row < 49) {
      const short8 xv = *(const short8*)(
          Pl + row * 80 + (((lane & 3) * 16) ^ ((row & 3) << 4)));
      *(short8*)(x_ws + ((size_t)wl * 49 + row) * 512 + h * 32 +
                 (lane & 3) * 8) = xv;
    }
  }
}

extern "C" void kernel_launch(void* const* d_in, const int* in_sizes, int n_in,
                              void* d_out, int out_size, void* d_ws,
                              size_t ws_size, hipStream_t stream) {
  const float* lf   = (const float*)d_in[0];
  const float* gfx  = (const float*)d_in[1];
  const float* mask = (const float*)d_in[2];
  const float* btab = (const float*)d_in[3];
  const float* Wk = (const float*)d_in[4];  const float* bk = (const float*)d_in[5];
  const float* Wq = (const float*)d_in[6];  const float* bq = (const float*)d_in[7];
  const float* Wv = (const float*)d_in[8];  const float* bv = (const float*)d_in[9];
  const float* Wp = (const float*)d_in[10]; const float* bp = (const float*)d_in[11];
  float* out = (float*)d_out;

  char* ws = (char*)d_ws;
  short* wbf = (short*)ws;  // 4 x 512x512 bf16 = 2 MB
  size_t off = (size_t)4 * 262144 * 2;
  float* rpbL = (float*)(ws + off); off += (size_t)16 * 4096 * 4;     // 256 KB
  float* maskL = (float*)(ws + off); off += (size_t)1024 * 4096 * 4;  // 16 MB

  const size_t perw = 50176 + 2 * 50176 + 65536;  // x,q,k + vT = 216064 B
  size_t avail = (ws_size > off + 65536) ? ws_size - off - 65536 : 0;
  int CH = (int)(avail / perw);
  if (CH > 4096) CH = 4096;
  if (CH < 1) CH = 1;

  bf16* x_ws = (bf16*)(ws + off); off += (size_t)CH * 50176;
  bf16* q_ws = (bf16*)(ws + off); off += (size_t)CH * 50176;
  bf16* k_ws = (bf16*)(ws + off); off += (size_t)CH * 50176;
  bf16* vT_ws = (bf16*)(ws + off); off += (size_t)CH * 65536;

  cvt_w_kernel<<<256, 256, 0, stream>>>(Wk, Wq, Wv, Wp, (bf16*)wbf);
  prep_rpbL<<<64, 256, 0, stream>>>(btab, rpbL);
  prep_maskL<<<4096, 256, 0, stream>>>(mask, maskL);

  const float qscale = 0.17677669529663687f;  // 1/sqrt(32)
  for (int wstart = 0; wstart < 4096; wstart += CH) {
    const int nwin = (4096 - wstart < CH) ? (4096 - wstart) : CH;
    const int M = nwin * 49;
    const int gy = (M + 127) / 128;
    gemm_kqv<<<6 * gy, 512, 0, stream>>>(lf + (size_t)wstart * 25088,
                                         gfx + (size_t)wstart * 25088, wbf,
                                         bk, bq, bv, qscale, k_ws, q_ws,
                                         vT_ws, M);
    attn_win2<<<dim3(nwin, 4), 256, 0, stream>>>(q_ws, k_ws, vT_ws, rpbL,
                                                 maskL, x_ws, wstart);
    gemm_p<<<2 * gy, 512, 0, stream>>>((const short*)x_ws, wbf + 3 * 262144,
                                       bp, out + (size_t)wstart * 25088, M);
  }
}